// Round 7
// baseline (916.572 us; speedup 1.0000x reference)
//
#include <hip/hip_runtime.h>
#include <stdint.h>

#define Hh    51
#define Bsz   1024
#define Tin   512
#define Ttot  576      // Tin + future(64)
#define NBB   2        // batches per block (grid 512 -> 2 blocks/CU for TLP)
#define BROWS 2        // LDS batch rows (mirror trick: col nn reads row nn&1)
#define NW    7        // waves per block; each wave owns 2 M-tiles (14 >= 13)
#define BLK   (NW*64)  // 448
#define BST   136      // per-batch k-stride (uint16) = 68 dwords
#define WS    18       // wsum per-wave stride (16 partials + 2 pad)

#define L2E   1.4426950408889634f    // log2(e)
#define TL2E  2.8853900817779268f    // 2*log2(e)

typedef __attribute__((ext_vector_type(8))) _Float16 half8;  // 8 x f16 frag
typedef __attribute__((ext_vector_type(4))) float f32x4;     // C/D frag

__device__ __forceinline__ float rcpf(float x){ return __builtin_amdgcn_rcpf(x); }
__device__ __forceinline__ float exp2f_fast(float x){
#if __has_builtin(__builtin_amdgcn_exp2f)
    return __builtin_amdgcn_exp2f(x);
#else
    return exp2f(x);
#endif
}

// Fused LSTM pointwise, rcp-merged: 7 trans ops.
// Inputs pre-scaled: vi,vf,vo by log2e; vg by 2log2e. Updates c, returns h.
__device__ __forceinline__ float cell_fuse(float vi, float vf, float vg,
                                           float vo, float& c){
    float Ei = exp2f_fast(-vi), Ef = exp2f_fast(-vf), Eg = exp2f_fast(-vg);
    float A = 1.f + Ef, B = 1.f + Ei, C = 1.f + Eg, D = 1.f - Eg;
    float BC = B*C;
    float R  = rcpf(A*BC);
    float cn = __builtin_fmaf(c, BC*R, (A*D)*R);
    c = cn;
    float Ec = exp2f_fast(fminf(-cn*TL2E, 120.f));
    float Eo = exp2f_fast(-vo);
    float R2 = rcpf((1.f+Eo)*(1.f+Ec));
    return (1.f - Ec) * R2;
}

__device__ __forceinline__ uint16_t f2h(float f){
    union{ _Float16 h; uint16_t u; } v; v.h = (_Float16)f;   // v_cvt_f16_f32 RNE
    return v.u;
}

// quad reduction (sum over lanes ^16 and ^32), R4/R6-proven shfl_xor chain.
__device__ __forceinline__ float qsum(float x){
    x += __shfl_xor(x, 16, 64);
    x += __shfl_xor(x, 32, 64);
    return x;
}
#define MFMA __builtin_amdgcn_mfma_f32_16x16x32_f16

// R21: cross-block TLP. R6 showed 1 block/CU, 128 CUs idle, >50% issue-slot
// stall on the step's dependency chain (ds_read -> MFMA -> cell -> qsum ->
// write -> barrier, plus wave-6 out-write straggler with its vmcnt(0) drain).
// The chain is irreducible per step, but an INDEPENDENT recurrence on the
// same CU fills the stalls: NBB 8->2 gives grid 512 = 2 blocks/CU on all
// 256 CUs. Mapping: ba = nn&1 (mirror broadcast now 8 lanes/address, still
// free); lanes with equal (quad, nn&1, nn<8) compute duplicate cells -- same
// value, same LDS address, benign. All per-block numerics identical to R6.
__global__ __launch_bounds__(BLK, 2)
void lstm_f16c(const float* __restrict__ inp,    // [B, Tin]
               const float* __restrict__ Wih1,   // [204, 1]
               const float* __restrict__ Whh1,   // [204, 51]
               const float* __restrict__ bih1,   // [204]
               const float* __restrict__ bhh1,   // [204]
               const float* __restrict__ Wih2,   // [204, 51]
               const float* __restrict__ Whh2,   // [204, 51]
               const float* __restrict__ bih2,   // [204]
               const float* __restrict__ bhh2,   // [204]
               const float* __restrict__ Wl,     // [1, 51]
               const float* __restrict__ blp,    // [1]
               float* __restrict__ outp)         // [B, Ttot]
{
    const int tid = threadIdx.x;
    const int wv  = tid >> 6, ln = tid & 63;
    const int quad = ln >> 4, nn = ln & 15;
    const bool lo = (nn < 8);
    const int ba  = nn & (NBB-1);      // batch owned/read by this lane
    const int b0  = blockIdx.x * NBB;

    __shared__ __align__(16) uint16_t Bh[2][BROWS*BST];
    __shared__ float wsum[2][NW*WS];      // parity-dbuf output partials

    for (int k = tid; k < BROWS*BST; k += BLK) { Bh[0][k] = 0; Bh[1][k] = 0; }
    if (tid < NW*WS) { wsum[0][tid] = 0.f; wsum[1][tid] = 0.f; }

    // ---- A fragments for 2 tiles; weights pre-scaled by log2e (2log2e for
    // g rows), single f16 product. Wave 6 tile 1 = all-zero dummy. ----
    half8 a1[2][2], a2[2][4];
    f32x4 bias1[2], bias2[2], wih1v[2];
    float wlu[2];
#pragma unroll
    for (int tl = 0; tl < 2; ++tl) {
        const bool tv = (wv + 7*tl) < 13;
        const int lr = 16*(wv + 7*tl) + nn;
        const int ua_ = lr >> 2, ga = lr & 3;
        const bool av = tv && (ua_ < Hh);
        const int pr = av ? (ga*Hh + ua_) : 0;
        const float rs = (ga == 2) ? TL2E : L2E;
#pragma unroll
        for (int s = 0; s < 2; ++s)
#pragma unroll
            for (int j = 0; j < 8; ++j) {
                int k = 32*s + quad*8 + j;
                float w = (av && k < Hh) ? Whh1[pr*Hh + k]*rs : 0.f;
                a1[tl][s][j] = (_Float16)w;
            }
#pragma unroll
        for (int s = 0; s < 4; ++s)
#pragma unroll
            for (int j = 0; j < 8; ++j) {
                int k = 32*s + quad*8 + j;
                float w = 0.f;
                if (av) {
                    if (k < Hh)                    w = Wih2[pr*Hh + k]*rs;
                    else if (k >= 64 && k < 64+Hh) w = Whh2[pr*Hh + (k-64)]*rs;
                }
                a2[tl][s][j] = (_Float16)w;
            }
        const int u = 4*(wv + 7*tl) + quad;
        const bool uv = tv && (u < Hh);
#pragma unroll
        for (int i = 0; i < 4; ++i) {
            int pri = uv ? (i*Hh + u) : 0;
            float gs = (i == 2) ? TL2E : L2E;
            bias1[tl][i] = uv ? (bih1[pri] + bhh1[pri])*gs : 0.f;
            bias2[tl][i] = uv ? (bih2[pri] + bhh2[pri])*gs : 0.f;
            wih1v[tl][i] = uv ? Wih1[pri]*gs : 0.f;
        }
        wlu[tl] = uv ? Wl[u] : 0.f;
    }
    const float blv = blp[0];

    // ---- assigned cell for this lane: (ua, ba); c-state lives here ----
    const int  ua  = 4*(wv + (lo ? 0 : 7)) + quad;
    const bool uva = (ua < Hh);
    const float wlua = lo ? wlu[0] : wlu[1];
    float c1 = 0.f, c2 = 0.f;

    // ---- prologue: h1(0) for assigned cell (pure per-lane math) ----
    {
        float b1a[4], w1a[4];
#pragma unroll
        for (int i = 0; i < 4; ++i) {
            b1a[i] = lo ? bias1[0][i] : bias1[1][i];
            w1a[i] = lo ? wih1v[0][i] : wih1v[1][i];
        }
        float x0 = inp[(size_t)(b0 + ba)*Tin];
        float vi = __builtin_fmaf(w1a[0], x0, b1a[0]);
        float vf = __builtin_fmaf(w1a[1], x0, b1a[1]);
        float vg = __builtin_fmaf(w1a[2], x0, b1a[2]);
        float vo = __builtin_fmaf(w1a[3], x0, b1a[3]);
        float h1n = cell_fuse(vi, vf, vg, vo, c1);
        if (uva) Bh[0][ba*BST + ua] = f2h(h1n);
    }
    float xreg = (Tin > 1) ? inp[(size_t)(b0 + ba)*Tin + 1] : 0.f;  // x(1), all lanes
    __syncthreads();

    // ================= input-mode loop: t in [0, Tin-1) =================
    for (int t = 0; t < Tin-1; ++t) {
        const int cur = t & 1, nxt = cur ^ 1;

        // ---- B-frag reads first (start LDS latency early). All cols nn
        // with equal nn&1 read the SAME row -> LDS broadcast; every acc
        // column holds real gates for batch nn&1. ----
        const uint16_t* rb = &Bh[cur][ba*BST + quad*8];
        half8 s0 = *(const half8*)(rb),      s1 = *(const half8*)(rb + 32);
        half8 s2 = *(const half8*)(rb + 64), s3 = *(const half8*)(rb + 96);

        // out(t-1) write (wave NW-1 only; reads previous phase's wsum[nxt])
        if (wv == NW-1 && t > 0) {
            float osum = blv;
#pragma unroll
            for (int w = 0; w < NW; ++w)
                osum += wsum[nxt][w*WS + ba] + wsum[nxt][w*WS + 8 + ba];
            if (ln < NBB) outp[(size_t)(b0 + ln)*Ttot + (t-1)] = osum;
        }
        float xn = (t + 2 < Tin) ? inp[(size_t)(b0 + ba)*Tin + t + 2] : 0.f;

        // ---- flat MFMA issue: L2(t) both tiles + L1(t+1) both tiles ----
        f32x4 aA0 = bias2[0], aB0 = {0.f,0.f,0.f,0.f};
        f32x4 aA1 = bias2[1], aB1 = {0.f,0.f,0.f,0.f};
        f32x4 bA0, bA1, bB0 = {0.f,0.f,0.f,0.f}, bB1 = {0.f,0.f,0.f,0.f};
#pragma unroll
        for (int i = 0; i < 4; ++i) {
            bA0[i] = __builtin_fmaf(wih1v[0][i], xreg, bias1[0][i]);
            bA1[i] = __builtin_fmaf(wih1v[1][i], xreg, bias1[1][i]);
        }
        aA0 = MFMA(a2[0][0], s0, aA0, 0,0,0);  aB0 = MFMA(a2[0][1], s1, aB0, 0,0,0);
        aA1 = MFMA(a2[1][0], s0, aA1, 0,0,0);  aB1 = MFMA(a2[1][1], s1, aB1, 0,0,0);
        bA0 = MFMA(a1[0][0], s0, bA0, 0,0,0);  bB0 = MFMA(a1[0][1], s1, bB0, 0,0,0);
        bA1 = MFMA(a1[1][0], s0, bA1, 0,0,0);  bB1 = MFMA(a1[1][1], s1, bB1, 0,0,0);
        aA0 = MFMA(a2[0][2], s2, aA0, 0,0,0);  aB0 = MFMA(a2[0][3], s3, aB0, 0,0,0);
        aA1 = MFMA(a2[1][2], s2, aA1, 0,0,0);  aB1 = MFMA(a2[1][3], s3, aB1, 0,0,0);

        // ---- select own tile's gates (no shuffle needed) ----
        f32x4 g2t0 = aA0 + aB0, g2t1 = aA1 + aB1;
        f32x4 g1t0 = bA0 + bB0, g1t1 = bA1 + bB1;
        float g2[4], g1[4];
#pragma unroll
        for (int i = 0; i < 4; ++i) {
            g2[i] = lo ? g2t0[i] : g2t1[i];
            g1[i] = lo ? g1t0[i] : g1t1[i];
        }

        // ---- 2 independent cell chains per lane; stores issue ASAP ----
        float h2v = cell_fuse(g2[0], g2[1], g2[2], g2[3], c2);
        float h1v = cell_fuse(g1[0], g1[1], g1[2], g1[3], c1);
        if (uva) {
            Bh[nxt][ba*BST + 64 + ua] = f2h(h2v);
            Bh[nxt][ba*BST      + ua] = f2h(h1v);
        }
        // quad reduction; partials per (tile, col); reader uses cols ba, 8+ba
        float part = qsum(wlua * h2v);
        if (ln < 16) wsum[cur][wv*WS + ln] = part;

        __syncthreads();
        xreg = xn;
    }

    // ================= future loop: t in [Tin-1, Ttot) =================
    for (int t = Tin-1; t < Ttot; ++t) {
        const int cur = t & 1, nxt = cur ^ 1;

        const uint16_t* rb = &Bh[cur][ba*BST + quad*8];
        half8 s0 = *(const half8*)(rb),      s1 = *(const half8*)(rb + 32);
        half8 s2 = *(const half8*)(rb + 64), s3 = *(const half8*)(rb + 96);

        if (wv == NW-1) {       // t >= 511 > 0 always
            float osum = blv;
#pragma unroll
            for (int w = 0; w < NW; ++w)
                osum += wsum[nxt][w*WS + ba] + wsum[nxt][w*WS + 8 + ba];
            if (ln < NBB) outp[(size_t)(b0 + ln)*Ttot + (t-1)] = osum;
        }

        // ---- L2(t), both tiles flat ----
        f32x4 aA0 = bias2[0], aB0 = {0.f,0.f,0.f,0.f};
        f32x4 aA1 = bias2[1], aB1 = {0.f,0.f,0.f,0.f};
        aA0 = MFMA(a2[0][0], s0, aA0, 0,0,0);  aB0 = MFMA(a2[0][1], s1, aB0, 0,0,0);
        aA1 = MFMA(a2[1][0], s0, aA1, 0,0,0);  aB1 = MFMA(a2[1][1], s1, aB1, 0,0,0);
        aA0 = MFMA(a2[0][2], s2, aA0, 0,0,0);  aB0 = MFMA(a2[0][3], s3, aB0, 0,0,0);
        aA1 = MFMA(a2[1][2], s2, aA1, 0,0,0);  aB1 = MFMA(a2[1][3], s3, aB1, 0,0,0);
        f32x4 g2t0 = aA0 + aB0, g2t1 = aA1 + aB1;
        float g2[4];
#pragma unroll
        for (int i = 0; i < 4; ++i) g2[i] = lo ? g2t0[i] : g2t1[i];
        float h2v = cell_fuse(g2[0], g2[1], g2[2], g2[3], c2);
        if (uva) Bh[nxt][ba*BST + 64 + ua] = f2h(h2v);
        float part = qsum(wlua * h2v);
        if (ln < 16) wsum[cur][wv*WS + ln] = part;
        __syncthreads();                                   // bar 1

        // ---- x(t+1) = out(t), then L1(t+1), both tiles flat ----
        if (t + 1 < Ttot) {
            float osum = blv;
#pragma unroll
            for (int w = 0; w < NW; ++w)
                osum += wsum[cur][w*WS + ba] + wsum[cur][w*WS + 8 + ba];
            f32x4 bA0, bA1, bB0 = {0.f,0.f,0.f,0.f}, bB1 = {0.f,0.f,0.f,0.f};
#pragma unroll
            for (int i = 0; i < 4; ++i) {
                bA0[i] = __builtin_fmaf(wih1v[0][i], osum, bias1[0][i]);
                bA1[i] = __builtin_fmaf(wih1v[1][i], osum, bias1[1][i]);
            }
            bA0 = MFMA(a1[0][0], s0, bA0, 0,0,0);  bB0 = MFMA(a1[0][1], s1, bB0, 0,0,0);
            bA1 = MFMA(a1[1][0], s0, bA1, 0,0,0);  bB1 = MFMA(a1[1][1], s1, bB1, 0,0,0);
            f32x4 g1t0 = bA0 + bB0, g1t1 = bA1 + bB1;
            float g1[4];
#pragma unroll
            for (int i = 0; i < 4; ++i) g1[i] = lo ? g1t0[i] : g1t1[i];
            float h1v = cell_fuse(g1[0], g1[1], g1[2], g1[3], c1);
            if (uva) Bh[nxt][ba*BST + ua] = f2h(h1v);
            __syncthreads();                               // bar 2 (future only)
        }
    }

    // final output (t = Ttot-1): wsum[(Ttot-1)&1] visible after last barrier
    if (wv == NW-1) {
        float osum = blv;
#pragma unroll
        for (int w = 0; w < NW; ++w)
            osum += wsum[(Ttot-1)&1][w*WS + ba] + wsum[(Ttot-1)&1][w*WS + 8 + ba];
        if (ln < NBB) outp[(size_t)(b0 + ln)*Ttot + (Ttot-1)] = osum;
    }
}

extern "C" void kernel_launch(void* const* d_in, const int* in_sizes, int n_in,
                              void* d_out, int out_size, void* d_ws, size_t ws_size,
                              hipStream_t stream) {
    (void)in_sizes; (void)n_in; (void)out_size; (void)d_ws; (void)ws_size;
    lstm_f16c<<<dim3(Bsz / NBB), dim3(BLK), 0, stream>>>(
        (const float*)d_in[0], (const float*)d_in[1],
        (const float*)d_in[2], (const float*)d_in[3],
        (const float*)d_in[4], (const float*)d_in[5],
        (const float*)d_in[6], (const float*)d_in[7],
        (const float*)d_in[8], (const float*)d_in[9],
        (const float*)d_in[10], (float*)d_out);
}

// Round 8
// 515.371 us; speedup vs baseline: 1.7785x; 1.7785x over previous
//
#include <hip/hip_runtime.h>
#include <stdint.h>

#define Hh    51
#define Bsz   1024
#define Tin   512
#define Ttot  576      // Tin + future(64)
#define NBB   8        // batches per block (grid 128)
#define BROWS 8        // LDS batch rows (mirror trick: cols 8-15 read row nn&7)
#define NW    7        // waves per block; each wave owns 2 M-tiles (14 >= 13)
#define BLK   (NW*64)  // 448
#define BST   136      // per-batch k-stride (uint16) = 68 dwords
#define WS    18       // wsum per-wave stride (16 partials + 2 pad)

#define L2E   1.4426950408889634f    // log2(e)
#define TL2E  2.8853900817779268f    // 2*log2(e)

typedef __attribute__((ext_vector_type(8))) _Float16 half8;  // 8 x f16 frag
typedef __attribute__((ext_vector_type(4))) float f32x4;     // C/D frag

__device__ __forceinline__ float rcpf(float x){ return __builtin_amdgcn_rcpf(x); }
__device__ __forceinline__ float exp2f_fast(float x){
#if __has_builtin(__builtin_amdgcn_exp2f)
    return __builtin_amdgcn_exp2f(x);
#else
    return exp2f(x);
#endif
}

// Fused LSTM pointwise, rcp-merged: 7 trans ops.
// Inputs pre-scaled: vi,vf,vo by log2e; vg by 2log2e. Updates c, returns h.
__device__ __forceinline__ float cell_fuse(float vi, float vf, float vg,
                                           float vo, float& c){
    float Ei = exp2f_fast(-vi), Ef = exp2f_fast(-vf), Eg = exp2f_fast(-vg);
    float A = 1.f + Ef, B = 1.f + Ei, C = 1.f + Eg, D = 1.f - Eg;
    float BC = B*C;
    float R  = rcpf(A*BC);
    float cn = __builtin_fmaf(c, BC*R, (A*D)*R);
    c = cn;
    float Ec = exp2f_fast(fminf(-cn*TL2E, 120.f));
    float Eo = exp2f_fast(-vo);
    float R2 = rcpf((1.f+Eo)*(1.f+Ec));
    return (1.f - Ec) * R2;
}

__device__ __forceinline__ uint16_t f2h(float f){
    union{ _Float16 h; uint16_t u; } v; v.h = (_Float16)f;   // v_cvt_f16_f32 RNE
    return v.u;
}

// quad reduction (sum over lanes ^16 and ^32), R4/R6-proven shfl_xor chain.
__device__ __forceinline__ float qsum(float x){
    x += __shfl_xor(x, 16, 64);
    x += __shfl_xor(x, 32, 64);
    return x;
}
#define MFMA __builtin_amdgcn_mfma_f32_16x16x32_f16

// R22 (R6 base; R7's 2-blocks/CU reverted -- zero cross-block overlap, 2x
// regression). New: the per-step global out-store drained at every barrier
// (compiler emits s_waitcnt vmcnt(0) before s_barrier; the store issues LATE
// in the body, so its write-ack lands on the barrier for all 7 waves). Fix:
// wave-6-private LDS ring oring[8][8]; per-step osum -> LDS write; every 8th
// step the ring is flushed at BODY START as 2 aligned float4 stores/batch,
// giving ~1900 cy of body to drain before that step's barrier. Outputs are
// bit-identical to R6; only the store schedule changes.
__global__ __launch_bounds__(BLK, 2)
void lstm_f16d(const float* __restrict__ inp,    // [B, Tin]
               const float* __restrict__ Wih1,   // [204, 1]
               const float* __restrict__ Whh1,   // [204, 51]
               const float* __restrict__ bih1,   // [204]
               const float* __restrict__ bhh1,   // [204]
               const float* __restrict__ Wih2,   // [204, 51]
               const float* __restrict__ Whh2,   // [204, 51]
               const float* __restrict__ bih2,   // [204]
               const float* __restrict__ bhh2,   // [204]
               const float* __restrict__ Wl,     // [1, 51]
               const float* __restrict__ blp,    // [1]
               float* __restrict__ outp)         // [B, Ttot]
{
    const int tid = threadIdx.x;
    const int wv  = tid >> 6, ln = tid & 63;
    const int quad = ln >> 4, nn = ln & 15;
    const bool lo = (nn < 8);
    const int ba  = nn & 7;            // batch owned/read by this lane
    const int b0  = blockIdx.x * NBB;

    __shared__ __align__(16) uint16_t Bh[2][BROWS*BST];
    __shared__ float wsum[2][NW*WS];      // parity-dbuf output partials
    __shared__ float oring[8][NBB];       // wave-6-private output ring

    for (int k = tid; k < BROWS*BST; k += BLK) { Bh[0][k] = 0; Bh[1][k] = 0; }
    if (tid < NW*WS) { wsum[0][tid] = 0.f; wsum[1][tid] = 0.f; }

    // ---- A fragments for 2 tiles; weights pre-scaled by log2e (2log2e for
    // g rows), single f16 product. Wave 6 tile 1 = all-zero dummy. ----
    half8 a1[2][2], a2[2][4];
    f32x4 bias1[2], bias2[2], wih1v[2];
    float wlu[2];
#pragma unroll
    for (int tl = 0; tl < 2; ++tl) {
        const bool tv = (wv + 7*tl) < 13;
        const int lr = 16*(wv + 7*tl) + nn;
        const int ua_ = lr >> 2, ga = lr & 3;
        const bool av = tv && (ua_ < Hh);
        const int pr = av ? (ga*Hh + ua_) : 0;
        const float rs = (ga == 2) ? TL2E : L2E;
#pragma unroll
        for (int s = 0; s < 2; ++s)
#pragma unroll
            for (int j = 0; j < 8; ++j) {
                int k = 32*s + quad*8 + j;
                float w = (av && k < Hh) ? Whh1[pr*Hh + k]*rs : 0.f;
                a1[tl][s][j] = (_Float16)w;
            }
#pragma unroll
        for (int s = 0; s < 4; ++s)
#pragma unroll
            for (int j = 0; j < 8; ++j) {
                int k = 32*s + quad*8 + j;
                float w = 0.f;
                if (av) {
                    if (k < Hh)                    w = Wih2[pr*Hh + k]*rs;
                    else if (k >= 64 && k < 64+Hh) w = Whh2[pr*Hh + (k-64)]*rs;
                }
                a2[tl][s][j] = (_Float16)w;
            }
        const int u = 4*(wv + 7*tl) + quad;
        const bool uv = tv && (u < Hh);
#pragma unroll
        for (int i = 0; i < 4; ++i) {
            int pri = uv ? (i*Hh + u) : 0;
            float gs = (i == 2) ? TL2E : L2E;
            bias1[tl][i] = uv ? (bih1[pri] + bhh1[pri])*gs : 0.f;
            bias2[tl][i] = uv ? (bih2[pri] + bhh2[pri])*gs : 0.f;
            wih1v[tl][i] = uv ? Wih1[pri]*gs : 0.f;
        }
        wlu[tl] = uv ? Wl[u] : 0.f;
    }
    const float blv = blp[0];

    // ---- assigned cell for this lane: (ua, ba); c-state lives here ----
    const int  ua  = 4*(wv + (lo ? 0 : 7)) + quad;
    const bool uva = (ua < Hh);
    const float wlua = lo ? wlu[0] : wlu[1];
    float c1 = 0.f, c2 = 0.f;

    // ---- prologue: h1(0) for assigned cell (pure per-lane math) ----
    {
        float b1a[4], w1a[4];
#pragma unroll
        for (int i = 0; i < 4; ++i) {
            b1a[i] = lo ? bias1[0][i] : bias1[1][i];
            w1a[i] = lo ? wih1v[0][i] : wih1v[1][i];
        }
        float x0 = inp[(size_t)(b0 + ba)*Tin];
        float vi = __builtin_fmaf(w1a[0], x0, b1a[0]);
        float vf = __builtin_fmaf(w1a[1], x0, b1a[1]);
        float vg = __builtin_fmaf(w1a[2], x0, b1a[2]);
        float vo = __builtin_fmaf(w1a[3], x0, b1a[3]);
        float h1n = cell_fuse(vi, vf, vg, vo, c1);
        if (uva) Bh[0][ba*BST + ua] = f2h(h1n);
    }
    float xreg = (Tin > 1) ? inp[(size_t)(b0 + ba)*Tin + 1] : 0.f;  // x(1), all lanes
    __syncthreads();

    // ================= input-mode loop: t in [0, Tin-1) =================
    for (int t = 0; t < Tin-1; ++t) {
        const int cur = t & 1, nxt = cur ^ 1;

        // ---- B-frag reads first (start LDS latency early); mirror rows ----
        const uint16_t* rb = &Bh[cur][ba*BST + quad*8];
        half8 s0 = *(const half8*)(rb),      s1 = *(const half8*)(rb + 32);
        half8 s2 = *(const half8*)(rb + 64), s3 = *(const half8*)(rb + 96);

        // ---- out(t-1): LDS ring write; flush 8-at-a-time at body start
        // (stores get the whole body to drain before this step's barrier) ----
        if (wv == NW-1 && t > 0) {
            if ((t & 7) == 0 && t >= 8 && ln < NBB) {
                // flush outs t-9 .. t-2? no: ring currently holds osum(t-9..t-2);
                // osum(t-1) is written below, AFTER the flush of the previous
                // 8. Flush window: t-9.. -- keep it simple and exact:
                // entries 0..7 hold osum(t-8 .. t-1-? ) -- see note below.
                ;
            }
            float osum = blv;
#pragma unroll
            for (int w = 0; w < NW; ++w)
                osum += wsum[nxt][w*WS + ba] + wsum[nxt][w*WS + 8 + ba];
            if (ln < NBB) oring[(t-1) & 7][ln] = osum;
            // After writing entry (t-1)&7: when t&7==0 the ring holds
            // osum(t-8..t-1) complete -> flush as 2 float4 per batch.
            if ((t & 7) == 0 && ln < NBB) {
                float4 o0 = { oring[0][ln], oring[1][ln],
                              oring[2][ln], oring[3][ln] };
                float4 o1 = { oring[4][ln], oring[5][ln],
                              oring[6][ln], oring[7][ln] };
                float* op = &outp[(size_t)(b0 + ln)*Ttot + (t - 8)];
                *(float4*)(op)     = o0;
                *(float4*)(op + 4) = o1;
            }
        }
        float xn = (t + 2 < Tin) ? inp[(size_t)(b0 + ba)*Tin + t + 2] : 0.f;

        // ---- flat MFMA issue: L2(t) both tiles + L1(t+1) both tiles ----
        f32x4 aA0 = bias2[0], aB0 = {0.f,0.f,0.f,0.f};
        f32x4 aA1 = bias2[1], aB1 = {0.f,0.f,0.f,0.f};
        f32x4 bA0, bA1, bB0 = {0.f,0.f,0.f,0.f}, bB1 = {0.f,0.f,0.f,0.f};
#pragma unroll
        for (int i = 0; i < 4; ++i) {
            bA0[i] = __builtin_fmaf(wih1v[0][i], xreg, bias1[0][i]);
            bA1[i] = __builtin_fmaf(wih1v[1][i], xreg, bias1[1][i]);
        }
        aA0 = MFMA(a2[0][0], s0, aA0, 0,0,0);  aB0 = MFMA(a2[0][1], s1, aB0, 0,0,0);
        aA1 = MFMA(a2[1][0], s0, aA1, 0,0,0);  aB1 = MFMA(a2[1][1], s1, aB1, 0,0,0);
        bA0 = MFMA(a1[0][0], s0, bA0, 0,0,0);  bB0 = MFMA(a1[0][1], s1, bB0, 0,0,0);
        bA1 = MFMA(a1[1][0], s0, bA1, 0,0,0);  bB1 = MFMA(a1[1][1], s1, bB1, 0,0,0);
        aA0 = MFMA(a2[0][2], s2, aA0, 0,0,0);  aB0 = MFMA(a2[0][3], s3, aB0, 0,0,0);
        aA1 = MFMA(a2[1][2], s2, aA1, 0,0,0);  aB1 = MFMA(a2[1][3], s3, aB1, 0,0,0);

        // ---- select own tile's gates (no shuffle needed) ----
        f32x4 g2t0 = aA0 + aB0, g2t1 = aA1 + aB1;
        f32x4 g1t0 = bA0 + bB0, g1t1 = bA1 + bB1;
        float g2[4], g1[4];
#pragma unroll
        for (int i = 0; i < 4; ++i) {
            g2[i] = lo ? g2t0[i] : g2t1[i];
            g1[i] = lo ? g1t0[i] : g1t1[i];
        }

        // ---- 2 independent cell chains per lane; stores issue ASAP ----
        float h2v = cell_fuse(g2[0], g2[1], g2[2], g2[3], c2);
        float h1v = cell_fuse(g1[0], g1[1], g1[2], g1[3], c1);
        if (uva) {
            Bh[nxt][ba*BST + 64 + ua] = f2h(h2v);
            Bh[nxt][ba*BST      + ua] = f2h(h1v);
        }
        // quad reduction; 2 partials/wave (lo tile, hi tile)
        float part = qsum(wlua * h2v);
        if (ln < 16) wsum[cur][wv*WS + ln] = part;

        __syncthreads();
        xreg = xn;
    }

    // ---- inter-loop flush: ring entries 0..5 = osum(504..509) (written at
    // steps 505..510; last in-loop flush was t=504 covering 496..503) ----
    if (wv == NW-1 && ln < NBB) {
        const int base = (Tin - 8) & ~7;            // 504
#pragma unroll
        for (int k = 0; k < 6; ++k)
            outp[(size_t)(b0 + ln)*Ttot + base + k] = oring[k][ln];
    }

    // ================= future loop: t in [Tin-1, Ttot) =================
    for (int t = Tin-1; t < Ttot; ++t) {
        const int cur = t & 1, nxt = cur ^ 1;

        const uint16_t* rb = &Bh[cur][ba*BST + quad*8];
        half8 s0 = *(const half8*)(rb),      s1 = *(const half8*)(rb + 32);
        half8 s2 = *(const half8*)(rb + 64), s3 = *(const half8*)(rb + 96);

        if (wv == NW-1) {       // t >= 511 > 0 always
            float osum = blv;
#pragma unroll
            for (int w = 0; w < NW; ++w)
                osum += wsum[nxt][w*WS + ba] + wsum[nxt][w*WS + 8 + ba];
            if (ln < NBB) outp[(size_t)(b0 + ln)*Ttot + (t-1)] = osum;
        }

        // ---- L2(t), both tiles flat ----
        f32x4 aA0 = bias2[0], aB0 = {0.f,0.f,0.f,0.f};
        f32x4 aA1 = bias2[1], aB1 = {0.f,0.f,0.f,0.f};
        aA0 = MFMA(a2[0][0], s0, aA0, 0,0,0);  aB0 = MFMA(a2[0][1], s1, aB0, 0,0,0);
        aA1 = MFMA(a2[1][0], s0, aA1, 0,0,0);  aB1 = MFMA(a2[1][1], s1, aB1, 0,0,0);
        aA0 = MFMA(a2[0][2], s2, aA0, 0,0,0);  aB0 = MFMA(a2[0][3], s3, aB0, 0,0,0);
        aA1 = MFMA(a2[1][2], s2, aA1, 0,0,0);  aB1 = MFMA(a2[1][3], s3, aB1, 0,0,0);
        f32x4 g2t0 = aA0 + aB0, g2t1 = aA1 + aB1;
        float g2[4];
#pragma unroll
        for (int i = 0; i < 4; ++i) g2[i] = lo ? g2t0[i] : g2t1[i];
        float h2v = cell_fuse(g2[0], g2[1], g2[2], g2[3], c2);
        if (uva) Bh[nxt][ba*BST + 64 + ua] = f2h(h2v);
        float part = qsum(wlua * h2v);
        if (ln < 16) wsum[cur][wv*WS + ln] = part;
        __syncthreads();                                   // bar 1

        // ---- x(t+1) = out(t), then L1(t+1), both tiles flat ----
        if (t + 1 < Ttot) {
            float osum = blv;
#pragma unroll
            for (int w = 0; w < NW; ++w)
                osum += wsum[cur][w*WS + ba] + wsum[cur][w*WS + 8 + ba];
            f32x4 bA0, bA1, bB0 = {0.f,0.f,0.f,0.f}, bB1 = {0.f,0.f,0.f,0.f};
#pragma unroll
            for (int i = 0; i < 4; ++i) {
                bA0[i] = __builtin_fmaf(wih1v[0][i], osum, bias1[0][i]);
                bA1[i] = __builtin_fmaf(wih1v[1][i], osum, bias1[1][i]);
            }
            bA0 = MFMA(a1[0][0], s0, bA0, 0,0,0);  bB0 = MFMA(a1[0][1], s1, bB0, 0,0,0);
            bA1 = MFMA(a1[1][0], s0, bA1, 0,0,0);  bB1 = MFMA(a1[1][1], s1, bB1, 0,0,0);
            f32x4 g1t0 = bA0 + bB0, g1t1 = bA1 + bB1;
            float g1[4];
#pragma unroll
            for (int i = 0; i < 4; ++i) g1[i] = lo ? g1t0[i] : g1t1[i];
            float h1v = cell_fuse(g1[0], g1[1], g1[2], g1[3], c1);
            if (uva) Bh[nxt][ba*BST + ua] = f2h(h1v);
            __syncthreads();                               // bar 2 (future only)
        }
    }

    // final output (t = Ttot-1): wsum[(Ttot-1)&1] visible after last barrier
    if (wv == NW-1) {
        float osum = blv;
#pragma unroll
        for (int w = 0; w < NW; ++w)
            osum += wsum[(Ttot-1)&1][w*WS + ba] + wsum[(Ttot-1)&1][w*WS + 8 + ba];
        if (ln < NBB) outp[(size_t)(b0 + ln)*Ttot + (Ttot-1)] = osum;
    }
}

extern "C" void kernel_launch(void* const* d_in, const int* in_sizes, int n_in,
                              void* d_out, int out_size, void* d_ws, size_t ws_size,
                              hipStream_t stream) {
    (void)in_sizes; (void)n_in; (void)out_size; (void)d_ws; (void)ws_size;
    lstm_f16d<<<dim3(Bsz / NBB), dim3(BLK), 0, stream>>>(
        (const float*)d_in[0], (const float*)d_in[1],
        (const float*)d_in[2], (const float*)d_in[3],
        (const float*)d_in[4], (const float*)d_in[5],
        (const float*)d_in[6], (const float*)d_in[7],
        (const float*)d_in[8], (const float*)d_in[9],
        (const float*)d_in[10], (float*)d_out);
}